// Round 13
// baseline (25941.394 us; speedup 1.0000x reference)
//
#include <hip/hip_runtime.h>
#include <stdint.h>

typedef __attribute__((ext_vector_type(4))) float float4v;

static __device__ __forceinline__ float sigp(float x){ return 1.f/(1.f+expf(-x)); }

__global__ void sentf_k(float* __restrict__ o, int n, float v){
  int i = blockIdx.x*256 + threadIdx.x; if (i < n) o[i] = v;
}

// ---------------- prep: plink + histogram over (seq, link) ----------------
__global__ void prep_k(const int* __restrict__ links, const int* __restrict__ paths,
                       const int* __restrict__ seqs, int* __restrict__ plink,
                       int* __restrict__ cnt){
  int e = blockIdx.x*256 + threadIdx.x;
  if (e < 120000){
    int p = paths[e], s = seqs[e], l = links[e];
    plink[p*6 + s] = l;
    atomicAdd(&cnt[s*2000 + l], 1);
  }
}
__global__ void scan_k(const int* __restrict__ cnt, int* __restrict__ off, int* __restrict__ cur){
  __shared__ int part[256]; __shared__ int pref[256];
  int t = threadIdx.x;
  int lo = t*47, hi = lo+47; if (hi > 12000) hi = 12000;
  int s = 0;
  for (int i=lo;i<hi;i++) s += cnt[i];
  part[t] = s; __syncthreads();
  if (t==0){ int r=0; for (int i=0;i<256;i++){ pref[i]=r; r+=part[i]; } }
  __syncthreads();
  int r = pref[t];
  for (int i=lo;i<hi;i++){ off[i]=r; cur[i]=r; r+=cnt[i]; }
}
__global__ void fill2_k(const int* __restrict__ links, const int* __restrict__ paths,
                        const int* __restrict__ seqs, int* __restrict__ cur,
                        int* __restrict__ plist){
  int e = blockIdx.x*256 + threadIdx.x;
  if (e < 120000){
    int p = paths[e], s = seqs[e], l = links[e];
    int pos = atomicAdd(&cur[s*2000 + l], 1);
    plist[pos] = p;
  }
}

// ---------------- state init into both buffers: h = [x0, 0...] ----------------
__global__ void initf_k(const float* __restrict__ x0, float* __restrict__ H0,
                        float* __restrict__ H1, int Mreal){
  int i = blockIdx.x*256 + threadIdx.x;   // grid covers Mpad*512
  int m = i >> 9; int c = i & 511;
  float v = (c==0 && m < Mreal) ? x0[m] : 0.f;
  H0[i] = v; H1[i] = v;
}

// ---------------- VALU GEMM: C[M,N] = relu?(A[M,K] @ W[N,K]^T + bias) ----------------
__global__ __launch_bounds__(256,2) void gemmv_k(
    const float* __restrict__ A, int lda, const float* __restrict__ W,
    const float* __restrict__ bias, float* __restrict__ C,
    int M, int N, int K, int relu)
{
  __shared__ float sA[64*32];    // [row][k]
  __shared__ float sW[32*192];   // [k][vc]
  const int tid = threadIdx.x;
  const int colg = tid & 31, rowg = tid >> 5;
  const int m0 = blockIdx.x*64, n0 = blockIdx.y*192;
  float acc[8][6] = {};
  for (int k0 = 0; k0 < K; k0 += 32){
    __syncthreads();
#pragma unroll
    for (int u = 0; u < 2; ++u){
      int fi = tid + u*256; int row = fi >> 3, kq = fi & 7;
      float4v v = *(const float4v*)(A + (size_t)(m0+row)*lda + k0 + kq*4);
      *(float4v*)&sA[row*32 + kq*4] = v;
    }
#pragma unroll
    for (int u = 0; u < 6; ++u){
      int fi = tid + u*256; int vc = fi >> 3, kq = fi & 7;
      int wrow = n0 + vc;
      float4v v = {0.f,0.f,0.f,0.f};
      if (wrow < N) v = *(const float4v*)(W + (size_t)wrow*K + k0 + kq*4);
      sW[(kq*4+0)*192 + vc] = v.x;
      sW[(kq*4+1)*192 + vc] = v.y;
      sW[(kq*4+2)*192 + vc] = v.z;
      sW[(kq*4+3)*192 + vc] = v.w;
    }
    __syncthreads();
#pragma unroll
    for (int kk = 0; kk < 32; ++kk){
      float a[8], w[6];
#pragma unroll
      for (int j = 0; j < 8; ++j) a[j] = sA[(rowg*8+j)*32 + kk];
#pragma unroll
      for (int i = 0; i < 6; ++i) w[i] = sW[kk*192 + colg*6 + i];
#pragma unroll
      for (int j = 0; j < 8; ++j)
#pragma unroll
        for (int i = 0; i < 6; ++i) acc[j][i] = fmaf(a[j], w[i], acc[j][i]);
    }
  }
#pragma unroll
  for (int j = 0; j < 8; ++j){
    int m = m0 + rowg*8 + j;
#pragma unroll
    for (int i = 0; i < 6; ++i){
      int col = n0 + colg*6 + i;
      if (col >= N) continue;
      float v = acc[j][i] + (bias ? bias[col] : 0.f);
      if (relu) v = fmaxf(v, 0.f);
      if (m >= M) v = 0.f;
      C[(size_t)m*N + col] = v;
    }
  }
}

// ---------------- fused VALU GRU step: gh GEMM + gather(gi) + gates ----------------
// tile 64 rows x 64 cols x 3 gates. grid(x=Mpad/64, y=8). K=512.
__global__ __launch_bounds__(256,2) void gruv_k(
    const float* __restrict__ Hin, const float* __restrict__ Whh,
    const float* __restrict__ bhh, const float* __restrict__ GI,
    const int* __restrict__ plink, int s,
    float* __restrict__ Hout, int M)
{
  __shared__ float sA[64*32];    // [row][k]
  __shared__ float sW[32*192];   // [k][vc], vc = g*64 + cl
  const int tid = threadIdx.x;
  const int colg = tid & 31, rowg = tid >> 5;
  const int m0 = blockIdx.x*64, c0 = blockIdx.y*64;
  float acc[8][2][3] = {};
  for (int k0 = 0; k0 < 512; k0 += 32){
    __syncthreads();
#pragma unroll
    for (int u = 0; u < 2; ++u){
      int fi = tid + u*256; int row = fi >> 3, kq = fi & 7;
      float4v v = *(const float4v*)(Hin + (size_t)(m0+row)*512 + k0 + kq*4);
      *(float4v*)&sA[row*32 + kq*4] = v;
    }
#pragma unroll
    for (int u = 0; u < 6; ++u){
      int fi = tid + u*256; int vc = fi >> 3, kq = fi & 7;
      int g = vc >> 6, cl = vc & 63;
      float4v v = *(const float4v*)(Whh + (size_t)(g*512 + c0 + cl)*512 + k0 + kq*4);
      sW[(kq*4+0)*192 + vc] = v.x;
      sW[(kq*4+1)*192 + vc] = v.y;
      sW[(kq*4+2)*192 + vc] = v.z;
      sW[(kq*4+3)*192 + vc] = v.w;
    }
    __syncthreads();
#pragma unroll
    for (int kk = 0; kk < 32; ++kk){
      float a[8], w[2][3];
#pragma unroll
      for (int j = 0; j < 8; ++j) a[j] = sA[(rowg*8+j)*32 + kk];
#pragma unroll
      for (int g = 0; g < 3; ++g)
#pragma unroll
        for (int cc = 0; cc < 2; ++cc) w[cc][g] = sW[kk*192 + g*64 + colg*2 + cc];
#pragma unroll
      for (int j = 0; j < 8; ++j)
#pragma unroll
        for (int cc = 0; cc < 2; ++cc)
#pragma unroll
          for (int g = 0; g < 3; ++g)
            acc[j][cc][g] = fmaf(a[j], w[cc][g], acc[j][cc][g]);
    }
  }
#pragma unroll
  for (int j = 0; j < 8; ++j){
    int m = m0 + rowg*8 + j;
    if (m < M){
      int gr = plink ? plink[m*6 + s] : m;
      const float* gi = GI + (size_t)gr * 1536;
#pragma unroll
      for (int cc = 0; cc < 2; ++cc){
        int col = c0 + colg*2 + cc;
        float hold = Hin[(size_t)m*512 + col];
        float rr = sigp(gi[col]        + acc[j][cc][0] + bhh[col]);
        float zz = sigp(gi[512 + col]  + acc[j][cc][1] + bhh[512 + col]);
        float nn = tanhf(gi[1024 + col] + rr * (acc[j][cc][2] + bhh[1024 + col]));
        Hout[(size_t)m*512 + col] = (1.f - zz) * nn + zz * hold;
      }
    } else {
#pragma unroll
      for (int cc = 0; cc < 2; ++cc)
        Hout[(size_t)m*512 + c0 + colg*2 + cc] = 0.f;
    }
  }
}

// ---------------- per-step segment-sum (deterministic gather); grid 2048 ----------------
__global__ void aggv_k(const float* __restrict__ H, const int* __restrict__ plist,
                       const int* __restrict__ off, const int* __restrict__ cnt, int s,
                       float* __restrict__ AGG, int isFirst)
{
  int l = blockIdx.x, t = threadIdx.x;
  size_t b0 = (size_t)l*512 + t, b1 = b0 + 256;
  if (l >= 2000){ AGG[b0] = 0.f; AGG[b1] = 0.f; return; }
  int o = off[s*2000 + l], c = cnt[s*2000 + l];
  float a0 = isFirst ? 0.f : AGG[b0];
  float a1 = isFirst ? 0.f : AGG[b1];
  for (int i = 0; i < c; ++i){
    size_t p = (size_t)plist[o + i] * 512;
    a0 += H[p + t];
    a1 += H[p + 256 + t];
  }
  AGG[b0] = a0; AGG[b1] = a1;
}

// ---------------- final 128->1 dot per row — FLOAT32 output ----------------
__global__ void dotf_k(const float* __restrict__ T2, const float* __restrict__ w3,
                       const float* __restrict__ b3, float* __restrict__ out, int M)
{
  int lane = threadIdx.x & 63, w = threadIdx.x >> 6;
  int m = blockIdx.x * 4 + w;
  if (m >= M) return;
  float s = T2[(size_t)m*128 + lane] * w3[lane]
          + T2[(size_t)m*128 + 64 + lane] * w3[64 + lane];
#pragma unroll
  for (int off = 32; off; off >>= 1) s += __shfl_xor(s, off);
  if (lane == 0) out[m] = s + b3[0];
}

extern "C" void kernel_launch(void* const* d_in, const int* in_sizes, int n_in,
                              void* d_out, int out_size, void* d_ws, size_t ws_size,
                              hipStream_t stream)
{
  const int*   links = (const int*)d_in[0];
  const int*   paths = (const int*)d_in[1];
  const int*   seqs  = (const int*)d_in[2];
  const float* cap   = (const float*)d_in[3];
  const float* bw    = (const float*)d_in[4];
  const float* Wih_p = (const float*)d_in[5];
  const float* Whh_p = (const float*)d_in[6];
  const float* bih_p = (const float*)d_in[7];
  const float* bhh_p = (const float*)d_in[8];
  const float* Wih_l = (const float*)d_in[9];
  const float* Whh_l = (const float*)d_in[10];
  const float* bih_l = (const float*)d_in[11];
  const float* bhh_l = (const float*)d_in[12];
  const float* d_w1 = (const float*)d_in[13]; const float* d_b1 = (const float*)d_in[14];
  const float* d_w2 = (const float*)d_in[15]; const float* d_b2 = (const float*)d_in[16];
  const float* d_w3 = (const float*)d_in[17]; const float* d_b3 = (const float*)d_in[18];
  const float* j_w1 = (const float*)d_in[19]; const float* j_b1 = (const float*)d_in[20];
  const float* j_w2 = (const float*)d_in[21]; const float* j_b2 = (const float*)d_in[22];
  const float* j_w3 = (const float*)d_in[23]; const float* j_b3 = (const float*)d_in[24];
  float* out = (float*)d_out;          // <-- reference output dtype is float32

  const int Mp = 20032, Lp = 2048, E = 120000;
  char* p = (char*)d_ws;
  auto alloc = [&](size_t n){ char* r = p; p += (n + 255) & ~(size_t)255; return r; };
  float* P0  = (float*)alloc((size_t)Mp*512*4);
  float* P1  = (float*)alloc((size_t)Mp*512*4);
  float* L0  = (float*)alloc((size_t)Lp*512*4);
  float* L1  = (float*)alloc((size_t)Lp*512*4);
  float* LG  = (float*)alloc((size_t)Lp*1536*4);   // link gi; reused as GIL
  float* AGG = (float*)alloc((size_t)Lp*512*4);
  float* t1  = (float*)alloc((size_t)Mp*256*4);
  float* t2  = (float*)alloc((size_t)Mp*128*4);
  int* cnt2  = (int*)alloc(12000*4);
  int* off2  = (int*)alloc(12000*4);
  int* cur2  = (int*)alloc(12000*4);
  int* plist = (int*)alloc(120000*4);
  int* plink = (int*)alloc(120000*4);
  if ((size_t)(p - (char*)d_ws) > ws_size){
    sentf_k<<<(out_size+255)/256,256,0,stream>>>(out, out_size, 0.25f);
    return;
  }

  hipMemsetAsync(cnt2, 0, 12000*4, stream);
  prep_k<<<469,256,0,stream>>>(links, paths, seqs, plink, cnt2);
  scan_k<<<1,256,0,stream>>>(cnt2, off2, cur2);
  fill2_k<<<469,256,0,stream>>>(links, paths, seqs, cur2, plist);
  initf_k<<<(Mp*512)/256,256,0,stream>>>(bw, P0, P1, 20000);
  initf_k<<<(Lp*512)/256,256,0,stream>>>(cap, L0, L1, 2000);

  float* Pb[2] = {P0, P1};
  float* Lb[2] = {L0, L1};
  int pb = 0, lb = 0;
  for (int t = 0; t < 8; ++t) {
    // LG = link_h @ Wih_p^T + bih_p   (gi rows for path entries, gathered)
    gemmv_k<<<dim3(32,8),256,0,stream>>>(Lb[lb], 512, Wih_p, bih_p, LG, 2000, 1536, 512, 0);
    for (int s = 0; s < 6; ++s) {
      gruv_k<<<dim3(313,8),256,0,stream>>>(Pb[pb], Whh_p, bhh_p, LG, plink, s,
                                           Pb[pb^1], 20000);
      pb ^= 1;
      aggv_k<<<2048,256,0,stream>>>(Pb[pb], plist, off2, cnt2, s, AGG, (s==0)?1:0);
    }
    // GIL = agg @ Wih_l^T + bih_l (into LG); link_h = GRU(GIL, link_h)
    gemmv_k<<<dim3(32,8),256,0,stream>>>(AGG, 512, Wih_l, bih_l, LG, 2000, 1536, 512, 0);
    gruv_k<<<dim3(32,8),256,0,stream>>>(Lb[lb], Whh_l, bhh_l, LG, (const int*)0, 0,
                                        Lb[lb^1], 2000);
    lb ^= 1;
  }
  // final path state: pb flipped 48 times -> Pb[0]

  // readout: delay (float32 out)
  gemmv_k<<<dim3(313,2),256,0,stream>>>(Pb[0], 512, d_w1, d_b1, t1, 20000, 256, 512, 1);
  gemmv_k<<<dim3(313,1),256,0,stream>>>(t1, 256, d_w2, d_b2, t2, 20000, 128, 256, 1);
  dotf_k<<<5000,256,0,stream>>>(t2, d_w3, d_b3, out, 20000);
  // readout: jitter (float32 out)
  gemmv_k<<<dim3(313,2),256,0,stream>>>(Pb[0], 512, j_w1, j_b1, t1, 20000, 256, 512, 1);
  gemmv_k<<<dim3(313,1),256,0,stream>>>(t1, 256, j_w2, j_b2, t2, 20000, 128, 256, 1);
  dotf_k<<<5000,256,0,stream>>>(t2, j_w3, j_b3, out + 20000, 20000);
}